// Round 1
// baseline (1217.950 us; speedup 1.0000x reference)
//
#include <hip/hip_runtime.h>

// Problem constants (fixed by setup_inputs)
#define N_BATCH 4
#define OC 128
#define ICPG 16
#define GROUPS 8
#define H 256
#define W 256

// Effective fused weights: [o][c][r*3+s][phase(pi*2+pj)]  -> 128*16*9*4 floats
__device__ float g_weff[OC * ICPG * 9 * 4];

// y[n][o][2bi+pi][2bj+pj] = sum_{c,r,s} Weff[o][c][r][s][pi*2+pj] * x[n][g*16+c][bi+r-1][bj+s-1]
// Weff[o][c][r][s][ph] = 4 * sum_{dy,dx} w[o][c][dy][dx] * f[pi+dy-2(r-1)] * f[pj+dx-2(s-1)]
//   (f index valid in [0,3]; f is the raw filter — flip + gain folded in here)

__global__ void prep_weff(const float* __restrict__ w, const float* __restrict__ f) {
    int t = blockIdx.x * 256 + threadIdx.x;   // t = o*16 + c
    if (t >= OC * ICPG) return;
    float wl[9];
#pragma unroll
    for (int i = 0; i < 9; i++) wl[i] = w[t * 9 + i];
    float fl[4];
#pragma unroll
    for (int i = 0; i < 4; i++) fl[i] = f[i];
    float* out = g_weff + t * 36;
#pragma unroll
    for (int r = 0; r < 3; r++) {
#pragma unroll
        for (int s = 0; s < 3; s++) {
#pragma unroll
            for (int pi = 0; pi < 2; pi++) {
#pragma unroll
                for (int pj = 0; pj < 2; pj++) {
                    float acc = 0.f;
#pragma unroll
                    for (int dy = 0; dy < 3; dy++) {
                        int fy = pi + dy - 2 * (r - 1);
                        if (fy < 0 || fy > 3) continue;
#pragma unroll
                        for (int dx = 0; dx < 3; dx++) {
                            int fx = pj + dx - 2 * (s - 1);
                            if (fx < 0 || fx > 3) continue;
                            acc += wl[dy * 3 + dx] * fl[fy] * fl[fx];
                        }
                    }
                    out[(r * 3 + s) * 4 + pi * 2 + pj] = 4.f * acc;
                }
            }
        }
    }
}

__global__ __launch_bounds__(256) void conv_fused(const float* __restrict__ x,
                                                  float* __restrict__ y) {
    // grid: (bi, o, n); block: 256 threads = bj
    const int bj = threadIdx.x;   // 0..255 base col
    const int bi = blockIdx.x;    // 0..255 base row
    const int o  = blockIdx.y;    // 0..127 out channel
    const int n  = blockIdx.z;    // 0..3
    const int g  = o >> 4;

    const float* xb = x + ((size_t)(n * OC + g * ICPG)) * (H * W);
    const float* wp = g_weff + (size_t)o * ICPG * 36;

    float acc0 = 0.f, acc1 = 0.f, acc2 = 0.f, acc3 = 0.f;

    for (int c = 0; c < ICPG; c++) {
        const float* xc = xb + (size_t)c * (H * W);
#pragma unroll
        for (int r = 0; r < 3; r++) {
            const int iy = bi + r - 1;
            const bool vy = (unsigned)iy < (unsigned)H;
            const float* xr = xc + iy * W;
#pragma unroll
            for (int s = 0; s < 3; s++) {
                const int ix = bj + s - 1;
                const float xv = (vy && (unsigned)ix < (unsigned)W) ? xr[ix] : 0.f;
                const float4 wv = *(const float4*)(wp + ((c * 3 + r) * 3 + s) * 4);
                acc0 += xv * wv.x;
                acc1 += xv * wv.y;
                acc2 += xv * wv.z;
                acc3 += xv * wv.w;
            }
        }
    }

    float* yb = y + (((size_t)(n * OC + o) * 512) + 2 * bi) * 512 + 2 * bj;
    *(float2*)(yb)       = make_float2(acc0, acc1);
    *(float2*)(yb + 512) = make_float2(acc2, acc3);
}

extern "C" void kernel_launch(void* const* d_in, const int* in_sizes, int n_in,
                              void* d_out, int out_size, void* d_ws, size_t ws_size,
                              hipStream_t stream) {
    const float* x = (const float*)d_in[0];
    const float* f = (const float*)d_in[1];
    const float* w = (const float*)d_in[2];
    float* y = (float*)d_out;

    hipLaunchKernelGGL(prep_weff, dim3(8), dim3(256), 0, stream, w, f);

    dim3 grid(H, OC, N_BATCH);
    hipLaunchKernelGGL(conv_fused, grid, dim3(256), 0, stream, x, y);
}